// Round 1
// baseline (14771.152 us; speedup 1.0000x reference)
//
#include <hip/hip_runtime.h>
#include <hip/hip_bf16.h>

#define B_ 256
#define T_ 256
#define F_ 512
#define H_ 1024
#define A_ 1000
#define EPS_ 1e-7f

typedef __hip_bfloat16 bf16;

// ---------------------------------------------------------------------------
// State of knowledge (round 10):
//  - CORRECTNESS LOCKED (harness-verified at 31109.5 us): d_out FLOAT32
//    [action(256), loss(1)]; RNG = V4 partitionable xor-fold threefry
//    (o0^o1), key(42)->(0,42); gumbel-argmax with first-index tie-break;
//    dtype runtime-detect (bf16-packed vs fp32) from Wx bit patterns.
//    detect/sample/finalize/gemm/threefry below are byte-identical to the
//    verified version. DO NOT TOUCH.
//  - Round 10 = performance restructure only:
//      * old: 256 sequential fused GEMM launches, K=1536, 256 blocks,
//        1 wave/SIMD, 2x2 micro (4B LDS/FMA) -> ~6.7 TF, 31 ms.
//      * new: (a) XW = inputs@Wx + b_rnn precomputed in 8 t-chunks via
//        128x128-tile 8x8-micro fp32 GEMM (1B LDS/FMA, 8 waves/CU);
//        (b) scan step = LDS-free kernel: lane=batch, hT[k][m] transposed
//        layout -> coalesced h reads; Wh via wave-uniform float4 (s_load
//        candidates, SGPR fma operand); 2x16-k software pipeline.
//      * needs ~43 MB workspace; if ws_size < 45 MiB -> verbatim old path.
//  - Summation order per output is sequential over k (same class of fp32
//    rounding as verified version; actions are gumbel-dominated).
// ---------------------------------------------------------------------------
__global__ __launch_bounds__(256) void detect_kernel(
    const unsigned* __restrict__ wx_words, int* __restrict__ flag)
{
    __shared__ int cnt[256];
    const int tid = threadIdx.x;
    int c = 0;
    for (int k = tid; k < 65536; k += 256) {
        unsigned lo = wx_words[k] & 0xFFFFu;
        unsigned e = (lo >> 7) & 0xFFu;
        if (e >= 105u && e <= 126u) c++;   // |v| in [2^-22, 0.5]: bf16 weight-like
    }
    cnt[tid] = c;
    __syncthreads();
    for (int s = 128; s > 0; s >>= 1) {
        if (tid < s) cnt[tid] += cnt[tid + s];
        __syncthreads();
    }
    if (tid == 0) flag[0] = (cnt[0] > 32768) ? 1 : 0;   // 1 => bf16-packed
}

__device__ __forceinline__ float load_maybe(const void* p, long i, int isbf16)
{
    return isbf16 ? __bfloat162float(((const bf16*)p)[i])
                  : ((const float*)p)[i];
}

// ---------------------------------------------------------------------------
// OLD fused GEMM (verified): kept for fallback path and layers 2/3.
// ---------------------------------------------------------------------------
__global__ __launch_bounds__(256) void gemm_kernel(
    const void* __restrict__ A1, int a1_maybe, long a1_off, int lda1, int K1,
    const float* __restrict__ A2, int lda2, int K2,
    const void* __restrict__ Wa, const void* __restrict__ Wb,
    const void* __restrict__ bias,
    const int* __restrict__ flagp,
    float* __restrict__ C, int M, int N, int do_relu)
{
    const int flagv = flagp[0];          // uniform; L2-hit
    const int a1_bf = a1_maybe ? flagv : 0;

    __shared__ float As[32][33];
    __shared__ float Bs[32][33];

    const int tid = threadIdx.x;
    const int tx = tid & 15;
    const int ty = tid >> 4;
    const int n0 = blockIdx.x * 32;
    const int m0 = blockIdx.y * 32;

    float acc00 = 0.f, acc01 = 0.f, acc10 = 0.f, acc11 = 0.f;

    for (int part = 0; part < 2; ++part) {
        const void* Wp = part ? Wb : Wa;
        const int    K = part ? K2 : K1;
        if (part == 1 && (A2 == nullptr || K2 <= 0)) continue;

        for (int k0 = 0; k0 < K; k0 += 32) {
            #pragma unroll
            for (int i = 0; i < 4; ++i) {
                int idx = tid + i * 256;
                int r = idx >> 5, c = idx & 31;
                float av;
                if (part == 0) {
                    long off = a1_off + (long)(m0 + r) * lda1 + (k0 + c);
                    av = load_maybe(A1, off, a1_bf);
                } else {
                    av = A2[(long)(m0 + r) * lda2 + (k0 + c)];
                }
                As[r][c] = av;
                int n = n0 + c;
                Bs[r][c] = (n < N) ? load_maybe(Wp, (long)(k0 + r) * N + n, flagv)
                                   : 0.0f;
            }
            __syncthreads();
            #pragma unroll
            for (int k = 0; k < 32; ++k) {
                float a0 = As[ty * 2][k];
                float a1 = As[ty * 2 + 1][k];
                float b0 = Bs[k][tx * 2];
                float b1 = Bs[k][tx * 2 + 1];
                acc00 = fmaf(a0, b0, acc00); acc01 = fmaf(a0, b1, acc01);
                acc10 = fmaf(a1, b0, acc10); acc11 = fmaf(a1, b1, acc11);
            }
            __syncthreads();
        }
    }

    const int m = m0 + ty * 2;
    const int n = n0 + tx * 2;
    float bs0 = (n     < N) ? load_maybe(bias, n,     flagv) : 0.0f;
    float bs1 = (n + 1 < N) ? load_maybe(bias, n + 1, flagv) : 0.0f;
    float v00 = acc00 + bs0, v01 = acc01 + bs1;
    float v10 = acc10 + bs0, v11 = acc11 + bs1;
    if (do_relu) {
        v00 = fmaxf(v00, 0.f); v01 = fmaxf(v01, 0.f);
        v10 = fmaxf(v10, 0.f); v11 = fmaxf(v11, 0.f);
    }
    if (n     < N) C[(long)m * N + n]           = v00;
    if (n + 1 < N) C[(long)m * N + n + 1]       = v01;
    if (n     < N) C[(long)(m + 1) * N + n]     = v10;
    if (n + 1 < N) C[(long)(m + 1) * N + n + 1] = v11;
}

// ---------------------------------------------------------------------------
// NEW: XW chunk GEMM. C[8192][1024] = inputs_chunk @ Wx + b_rnn  (no relu).
// Chunk rows r = b*32 + tl  <->  input row b*256 + (t0 + tl).
// 128x128 tile, BK=16, 8x8 micro, 256 threads. Grid (8, 64).
// ---------------------------------------------------------------------------
__global__ __launch_bounds__(256, 2) void xw_gemm_kernel(
    const void* __restrict__ X,      // inputs, dual dtype
    const void* __restrict__ Wx,     // [512][1024], dual dtype
    const void* __restrict__ brnn,   // [1024], dual dtype
    const int* __restrict__ flagp,
    float* __restrict__ C,           // [8192][1024] chunk buffer
    int t0)
{
    const int flagv = flagp[0];
    __shared__ float As[16][132];    // k-major: As[k][m]
    __shared__ float Bs[16][132];    // Bs[k][n]

    const int tid = threadIdx.x;
    const int tx = tid & 15;
    const int ty = tid >> 4;
    const int n0 = blockIdx.x * 128;
    const int m0 = blockIdx.y * 128;

    float acc[8][8] = {{0.f}};

    for (int k0 = 0; k0 < F_; k0 += 16) {
        #pragma unroll
        for (int i = 0; i < 8; ++i) {
            int idx = tid + i * 256;            // 0..2047
            // A: 128 rows x 16 k, consecutive tid -> consecutive k
            int ka = idx & 15, r = idx >> 4;
            int rg = m0 + r;
            long irow = (long)(rg >> 5) * 256 + t0 + (rg & 31);
            As[ka][r] = load_maybe(X, irow * F_ + k0 + ka, flagv);
            // B: 16 k x 128 n, consecutive tid -> consecutive n
            int nb = idx & 127, kb = idx >> 7;
            Bs[kb][nb] = load_maybe(Wx, (long)(k0 + kb) * H_ + n0 + nb, flagv);
        }
        __syncthreads();
        #pragma unroll
        for (int k = 0; k < 16; ++k) {
            float4 a0 = *(const float4*)&As[k][ty * 4];
            float4 a1 = *(const float4*)&As[k][ty * 4 + 64];
            float4 b0 = *(const float4*)&Bs[k][tx * 4];
            float4 b1 = *(const float4*)&Bs[k][tx * 4 + 64];
            float av[8] = {a0.x, a0.y, a0.z, a0.w, a1.x, a1.y, a1.z, a1.w};
            float bv[8] = {b0.x, b0.y, b0.z, b0.w, b1.x, b1.y, b1.z, b1.w};
            #pragma unroll
            for (int i = 0; i < 8; ++i)
                #pragma unroll
                for (int j = 0; j < 8; ++j)
                    acc[i][j] = fmaf(av[i], bv[j], acc[i][j]);
        }
        __syncthreads();
    }

    float bb[8];
    #pragma unroll
    for (int j = 0; j < 8; ++j) {
        int n = n0 + tx * 4 + (j & 3) + (j >> 2) * 64;
        bb[j] = load_maybe(brnn, n, flagv);
    }
    #pragma unroll
    for (int i = 0; i < 8; ++i) {
        int m = m0 + ty * 4 + (i & 3) + (i >> 2) * 64;
        float4 v0 = {acc[i][0] + bb[0], acc[i][1] + bb[1],
                     acc[i][2] + bb[2], acc[i][3] + bb[3]};
        float4 v1 = {acc[i][4] + bb[4], acc[i][5] + bb[5],
                     acc[i][6] + bb[6], acc[i][7] + bb[7]};
        *(float4*)&C[(long)m * H_ + n0 + tx * 4]      = v0;
        *(float4*)&C[(long)m * H_ + n0 + tx * 4 + 64] = v1;
    }
}

// ---------------------------------------------------------------------------
// NEW: Wh -> fp32 copy (handles bf16-packed mode once, outside the scan).
// ---------------------------------------------------------------------------
__global__ __launch_bounds__(256) void convert_wh_kernel(
    const void* __restrict__ Wh, const int* __restrict__ flagp,
    float* __restrict__ whf)
{
    const int flagv = flagp[0];
    long i = (long)blockIdx.x * 256 + threadIdx.x;
    whf[i] = load_maybe(Wh, i, flagv);
}

// ---------------------------------------------------------------------------
// NEW: RNN scan step, LDS-free.
//   hTn[n][m] = relu( xw[m][tl][n] + sum_k hT[k][m] * Wh[k][n] )
// Layouts: hT/hTn = [H=1024 k][B=256 m] (transposed h). xw = chunk base
// already offset to tl (row stride 32*1024 per batch).
// Grid (64, 4), 256 threads = 4 waves. Wave w: cols n0 = bx*16 + w*4 .. +3
// (wave-uniform -> Wh loads scalarizable); lane l: m = by*64 + l.
// All 4 waves of a block share the same m-chunk -> the per-k 256B h read is
// L1-reused x4; per-CU L2 demand ~256 B/k. 2x16-k software pipeline hides
// load latency (only 1 wave/SIMD resident).
// ---------------------------------------------------------------------------
__global__ __launch_bounds__(256, 1) void rnn_step_kernel(
    const float* __restrict__ hT,     // [1024][256]
    const float* __restrict__ Wh,     // [1024][1024] fp32
    const float* __restrict__ xw,     // xwbuf + tl*1024
    float* __restrict__ hTn)          // [1024][256]
{
    const int tid  = threadIdx.x;
    const int lane = tid & 63;
    const int w    = __builtin_amdgcn_readfirstlane(tid >> 6);
    const int m    = blockIdx.y * 64 + lane;
    const int n0   = blockIdx.x * 16 + w * 4;

    const float* __restrict__ ap = hT + m;     // + k*256
    const float* __restrict__ bp = Wh + n0;    // + k*1024 (wave-uniform)

    float acc0 = 0.f, acc1 = 0.f, acc2 = 0.f, acc3 = 0.f;

    float  Xa[16]; float4 Xb[16];
    float  Ya[16]; float4 Yb[16];

#define LOADBLK(P, KOFF) do {                                              \
        _Pragma("unroll")                                                  \
        for (int i_ = 0; i_ < 16; ++i_) {                                  \
            P##a[i_] = ap[(long)((KOFF) + i_) << 8];                       \
            P##b[i_] = *(const float4*)(bp + ((long)((KOFF) + i_) << 10)); \
        } } while (0)

#define FMABLK(P) do {                                                     \
        _Pragma("unroll")                                                  \
        for (int i_ = 0; i_ < 16; ++i_) {                                  \
            acc0 = fmaf(P##a[i_], P##b[i_].x, acc0);                       \
            acc1 = fmaf(P##a[i_], P##b[i_].y, acc1);                       \
            acc2 = fmaf(P##a[i_], P##b[i_].z, acc2);                       \
            acc3 = fmaf(P##a[i_], P##b[i_].w, acc3);                       \
        } } while (0)

    LOADBLK(X, 0);
    for (int kb = 0; kb < 992; kb += 32) {     // kb = 0..960, 31 iters
        LOADBLK(Y, kb + 16);
        FMABLK(X);
        LOADBLK(X, kb + 32);
        FMABLK(Y);
    }
    LOADBLK(Y, 1008);
    FMABLK(X);                                  // k = 992..1007
    FMABLK(Y);                                  // k = 1008..1023

#undef LOADBLK
#undef FMABLK

    const float4 xv = *(const float4*)(xw + (long)m * (32 * 1024) + n0);
    float v0 = fmaxf(acc0 + xv.x, 0.f);
    float v1 = fmaxf(acc1 + xv.y, 0.f);
    float v2 = fmaxf(acc2 + xv.z, 0.f);
    float v3 = fmaxf(acc3 + xv.w, 0.f);
    hTn[(long)(n0 + 0) * 256 + m] = v0;
    hTn[(long)(n0 + 1) * 256 + m] = v1;
    hTn[(long)(n0 + 2) * 256 + m] = v2;
    hTn[(long)(n0 + 3) * 256 + m] = v3;
}

// ---------------------------------------------------------------------------
// NEW: transpose hT[1024][256] -> h_last[256][1024] for layer 2.
// ---------------------------------------------------------------------------
__global__ __launch_bounds__(256) void transpose_kernel(
    const float* __restrict__ in,   // [1024][256]
    float* __restrict__ out)        // [256][1024]
{
    __shared__ float t[32][33];
    const int tid = threadIdx.x;
    const int c  = tid & 31;
    const int r8 = tid >> 5;
    const int x0 = blockIdx.x * 32;   // over 1024
    const int y0 = blockIdx.y * 32;   // over 256
    #pragma unroll
    for (int i = 0; i < 4; ++i) {
        int r = r8 + i * 8;
        t[r][c] = in[(long)(x0 + r) * 256 + y0 + c];
    }
    __syncthreads();
    #pragma unroll
    for (int i = 0; i < 4; ++i) {
        int r = r8 + i * 8;
        out[(long)(y0 + r) * 1024 + x0 + c] = t[c][r];
    }
}

// ---------------------------------------------------------------------------
// Threefry2x32, 20 rounds — matches JAX exactly. key(42) => (k0,k1)=(0,42).
// ---------------------------------------------------------------------------
__device__ __forceinline__ unsigned rotl32(unsigned v, int r) {
    return (v << r) | (v >> (32 - r));
}

__device__ __forceinline__ void threefry2x32(unsigned k0, unsigned k1,
                                             unsigned x0, unsigned x1,
                                             unsigned& o0, unsigned& o1)
{
    unsigned ks2 = k0 ^ k1 ^ 0x1BD11BDAu;
    x0 += k0; x1 += k1;
#define R4(ra, rb, rc, rd)                              \
    x0 += x1; x1 = rotl32(x1, ra); x1 ^= x0;            \
    x0 += x1; x1 = rotl32(x1, rb); x1 ^= x0;            \
    x0 += x1; x1 = rotl32(x1, rc); x1 ^= x0;            \
    x0 += x1; x1 = rotl32(x1, rd); x1 ^= x0;
    R4(13, 15, 26, 6);  x0 += k1;  x1 += ks2 + 1u;
    R4(17, 29, 16, 24); x0 += ks2; x1 += k0  + 2u;
    R4(13, 15, 26, 6);  x0 += k0;  x1 += k1  + 3u;
    R4(17, 29, 16, 24); x0 += k1;  x1 += ks2 + 4u;
    R4(13, 15, 26, 6);  x0 += ks2; x1 += k0  + 5u;
#undef R4
    o0 = x0; o1 = x1;
}

// Gumbel at flat index j of the (256,1000) draw, key(42).
// V4 partitionable xor-fold (VERIFIED): counts (hi=0, lo=j), bits = o0^o1.
__device__ __forceinline__ float gumbel_at(unsigned j)
{
    unsigned o0, o1;
    threefry2x32(0u, 42u, 0u, j, o0, o1);
    unsigned bits = o0 ^ o1;                       // V4: xor-fold
    unsigned ub = (bits >> 9) | 0x3F800000u;       // [1,2)
    float u = __uint_as_float(ub) - 1.0f;          // [0,1)
    const float TINY = 1.1754943508222875e-38f;    // finfo(f32).tiny
    u = fmaxf(TINY, u * (1.0f - TINY) + TINY);     // JAX uniform(minval=tiny)
    return -logf(-logf(u));
}

// ---------------------------------------------------------------------------
// Softmax + gumbel-argmax sampling + loss. One block per batch row.
// OUTPUT IS FLOAT32. besti canary = 500.
// ---------------------------------------------------------------------------
__global__ __launch_bounds__(256) void sample_kernel(
    const float* __restrict__ logits,      // [B_, A_]
    float* __restrict__ out,               // out[b] = action as float32
    float* __restrict__ loss_acc)          // pre-zeroed scalar
{
    const int b = blockIdx.x;
    const int tid = threadIdx.x;
    const float* row = logits + (long)b * A_;

    __shared__ float sv[256];
    __shared__ int   si[256];

    // 1. row max
    float lv[4];
    float lmax = -INFINITY;
    #pragma unroll
    for (int i = 0; i < 4; ++i) {
        int a = tid + i * 256;
        lv[i] = (a < A_) ? row[a] : -INFINITY;
        lmax = fmaxf(lmax, lv[i]);
    }
    sv[tid] = lmax;
    __syncthreads();
    for (int s = 128; s > 0; s >>= 1) {
        if (tid < s) sv[tid] = fmaxf(sv[tid], sv[tid + s]);
        __syncthreads();
    }
    lmax = sv[0];
    __syncthreads();

    // 2. exp + sum
    float e[4];
    float lsum = 0.f;
    #pragma unroll
    for (int i = 0; i < 4; ++i) {
        int a = tid + i * 256;
        e[i] = (a < A_) ? expf(lv[i] - lmax) : 0.0f;
        lsum += e[i];
    }
    sv[tid] = lsum;
    __syncthreads();
    for (int s = 128; s > 0; s >>= 1) {
        if (tid < s) sv[tid] += sv[tid + s];
        __syncthreads();
    }
    const float inv = 1.0f / sv[0];
    __syncthreads();

    // 3. score = prob + gumbel; argmax, first-index tie-break (np.argmax)
    float bestv = -INFINITY;
    int   besti = 500;                     // NaN canary
    #pragma unroll
    for (int i = 0; i < 4; ++i) {
        int a = tid + i * 256;
        if (a < A_) {
            float score = e[i] * inv + gumbel_at((unsigned)(b * A_ + a));
            if (score > bestv) { bestv = score; besti = a; }
        }
    }
    sv[tid] = bestv; si[tid] = besti;
    __syncthreads();
    for (int s = 128; s > 0; s >>= 1) {
        if (tid < s) {
            float v2 = sv[tid + s]; int i2 = si[tid + s];
            if (v2 > sv[tid] || (v2 == sv[tid] && i2 < si[tid])) {
                sv[tid] = v2; si[tid] = i2;
            }
        }
        __syncthreads();
    }

    if (tid == 0) {
        int act = si[0];
        out[b] = (float)act;                       // float32 action
        float p = expf(row[act] - lmax) * inv;
        p = fminf(fmaxf(p, EPS_), 1.0f - EPS_);
        atomicAdd(loss_acc, -logf(p) * (1.0f / (float)B_));
    }
}

__global__ void finalize_kernel(const float* __restrict__ loss_acc,
                                float* __restrict__ out)
{
    out[B_] = *loss_acc;                           // float32 loss
}

// ---------------------------------------------------------------------------
extern "C" void kernel_launch(void* const* d_in, const int* in_sizes, int n_in,
                              void* d_out, int out_size, void* d_ws, size_t ws_size,
                              hipStream_t stream)
{
    (void)out_size;

    // Size-based pointer mapping (removes any ordering assumption).
    const void *inputs = nullptr, *Wx = nullptr, *Wh = nullptr, *b_rnn = nullptr,
               *W1 = nullptr, *b1 = nullptr, *W2 = nullptr, *b2 = nullptr;
    for (int i = 0; i < n_in; ++i) {
        int s = in_sizes[i];
        if      (s == 33554432) inputs = d_in[i];
        else if (s == 524288)   Wx = d_in[i];
        else if (s == 1048576)  { if (!Wh) Wh = d_in[i]; else W1 = d_in[i]; }
        else if (s == 1024)     { if (!b_rnn) b_rnn = d_in[i]; else b1 = d_in[i]; }
        else if (s == 1024000)  W2 = d_in[i];
        else if (s == 1000)     b2 = d_in[i];
    }
    if (!inputs) inputs = d_in[0];
    if (!Wx) Wx = d_in[1];  if (!Wh) Wh = d_in[2];  if (!b_rnn) b_rnn = d_in[3];
    if (!W1) W1 = d_in[4];  if (!b1) b1 = d_in[5];  if (!W2) W2 = d_in[6];
    if (!b2) b2 = d_in[7];

    float* out = (float*)d_out;            // FLOAT32 output buffer
    float* ws = (float*)d_ws;

    dim3 blk(256);
    dim3 grdH((H_ + 31) / 32, B_ / 32);   // 32 x 8
    dim3 grdA((A_ + 31) / 32, B_ / 32);

    // Workspace demand for the fast path (~43 MB in floats):
    const size_t XW_FLOATS = (size_t)8192 * 1024;     // 8,388,608 (32-t chunk)
    const size_t need_floats = XW_FLOATS + 2 * 262144 + 1048576
                             + 262144 + 262144 + 256000 + 2;
    if (ws_size >= need_floats * sizeof(float)) {
        // ---------------- FAST PATH (round 10) ----------------
        float* xwbuf    = ws;                          // [8192][1024]
        float* hT0      = xwbuf + XW_FLOATS;           // [1024][256]
        float* hT1      = hT0 + 262144;                // [1024][256]
        float* whf      = hT1 + 262144;                // [1024][1024]
        float* hlast    = whf + 1048576;               // [256][1024]
        float* hid      = hlast + 262144;              // [256][1024]
        float* logits   = hid + 262144;                // [256][1000]
        float* loss_acc = logits + 256000;             // [1]
        int*   flag     = (int*)(loss_acc + 1);        // [1]

        hipMemsetAsync(hT0, 0, 262144 * sizeof(float), stream);
        hipMemsetAsync(loss_acc, 0, sizeof(float), stream);

        // 0. dtype detect, Wh -> fp32
        detect_kernel<<<1, blk, 0, stream>>>((const unsigned*)Wx, flag);
        convert_wh_kernel<<<4096, blk, 0, stream>>>(Wh, flag, whf);

        // 1. scan: per 32-t chunk, precompute XW then run 32 steps
        float* hp = hT0;
        float* hn = hT1;
        for (int c = 0; c < 8; ++c) {
            xw_gemm_kernel<<<dim3(8, 64), blk, 0, stream>>>(
                inputs, Wx, b_rnn, flag, xwbuf, c * 32);
            for (int tl = 0; tl < 32; ++tl) {
                rnn_step_kernel<<<dim3(64, 4), blk, 0, stream>>>(
                    hp, whf, xwbuf + (long)tl * 1024, hn);
                float* tmp = hp; hp = hn; hn = tmp;
            }
        }

        // 2. hT -> h_last (natural layout) for the dense layers
        transpose_kernel<<<dim3(32, 8), blk, 0, stream>>>(hp, hlast);

        // 3. hid = relu(h_T @ W1 + b1); logits = hid @ W2 + b2
        gemm_kernel<<<grdH, blk, 0, stream>>>(
            hlast, 0, 0, H_, H_, nullptr, 0, 0, W1, nullptr, b1, flag,
            hid, B_, H_, 1);
        gemm_kernel<<<grdA, blk, 0, stream>>>(
            hid, 0, 0, H_, H_, nullptr, 0, 0, W2, nullptr, b2, flag,
            logits, B_, A_, 0);

        // 4. softmax -> gumbel argmax -> loss
        sample_kernel<<<dim3(B_), blk, 0, stream>>>(logits, out, loss_acc);
        finalize_kernel<<<1, 1, 0, stream>>>(loss_acc, out);
        return;
    }

    // ---------------- FALLBACK: verbatim verified path ----------------
    float* hA       = ws;                       // [B,H]
    float* hB       = hA + (long)B_ * H_;       // [B,H]
    float* hid      = hB + (long)B_ * H_;       // [B,H]
    float* logits   = hid + (long)B_ * H_;      // [B,A]
    float* loss_acc = logits + (long)B_ * A_;   // [1]
    int*   flag     = (int*)(loss_acc + 1);     // [1] dtype flag

    hipMemsetAsync(hA, 0, (size_t)B_ * H_ * sizeof(float), stream);
    hipMemsetAsync(loss_acc, 0, sizeof(float), stream);

    detect_kernel<<<1, blk, 0, stream>>>((const unsigned*)Wx, flag);

    float* hp = hA;
    float* hn = hB;
    for (int t = 0; t < T_; ++t) {
        gemm_kernel<<<grdH, blk, 0, stream>>>(
            inputs, 1, (long)t * F_, T_ * F_, F_,
            hp, H_, H_,
            Wx, Wh, b_rnn, flag,
            hn, B_, H_, 1);
        float* tmp = hp; hp = hn; hn = tmp;
    }

    gemm_kernel<<<grdH, blk, 0, stream>>>(
        hp, 0, 0, H_, H_, nullptr, 0, 0, W1, nullptr, b1, flag, hid, B_, H_, 1);
    gemm_kernel<<<grdA, blk, 0, stream>>>(
        hid, 0, 0, H_, H_, nullptr, 0, 0, W2, nullptr, b2, flag, logits, B_, A_, 0);

    sample_kernel<<<dim3(B_), blk, 0, stream>>>(logits, out, loss_acc);
    finalize_kernel<<<1, 1, 0, stream>>>(loss_acc, out);
}

// Round 3
// 5401.094 us; speedup vs baseline: 2.7348x; 2.7348x over previous
//
#include <hip/hip_runtime.h>
#include <hip/hip_bf16.h>

#define B_ 256
#define T_ 256
#define F_ 512
#define H_ 1024
#define A_ 1000
#define EPS_ 1e-7f

typedef __hip_bfloat16 bf16;

// ---------------------------------------------------------------------------
// State of knowledge (round 12 == round 11 resubmit; r11 bench was an infra
// failure, GPUAcquisitionTimeout — kernel never ran):
//  - CORRECTNESS LOCKED (harness-verified r9 @31109us, r10 @14771us, absmax
//    0.0): d_out FLOAT32 [action(256), loss(1)]; RNG = V4 partitionable
//    xor-fold threefry (o0^o1), key(42)->(0,42); gumbel-argmax first-index
//    tie-break; dtype runtime-detect from Wx bit patterns.
//    detect/sample/finalize/gemm/xw_gemm/threefry below are byte-identical
//    to the r10-verified version. DO NOT TOUCH.
//  - r10 lesson: scan went 256 fused GEMMs -> LDS-free step kernel, but at
//    grid 256x256t = 1 wave/SIMD the step ran ~40us (est), not ~4us:
//    latency + 64b addr-calc exposed with zero TLP.
//  - r11/r12: step kernel v2 = in-block split-K. 1024 threads = 16 waves:
//    wave (g=w&3 -> 4-col group, q=w>>2 -> 256-k quarter). 4 waves/SIMD
//    TLP replaces the manual pipeline; 12KB LDS float4 combine
//    (contiguous b128, conflict-free); fixed combine order q0+q1+q2+q3+xw.
//    Order changed vs r10 (was seq k then +xw) — r10 itself changed order
//    vs r9 and passed absmax 0.0, so this reordering class is tolerated.
//  - Decision tree on next counters: steps 4-7us & dominant -> persistent
//    scan / megakernel; steps >10us low VALUBusy -> Wh not scalarizing,
//    stage Wh in LDS; absmax!=0 -> revert to seq-k order variant.
// ---------------------------------------------------------------------------
__global__ __launch_bounds__(256) void detect_kernel(
    const unsigned* __restrict__ wx_words, int* __restrict__ flag)
{
    __shared__ int cnt[256];
    const int tid = threadIdx.x;
    int c = 0;
    for (int k = tid; k < 65536; k += 256) {
        unsigned lo = wx_words[k] & 0xFFFFu;
        unsigned e = (lo >> 7) & 0xFFu;
        if (e >= 105u && e <= 126u) c++;   // |v| in [2^-22, 0.5]: bf16 weight-like
    }
    cnt[tid] = c;
    __syncthreads();
    for (int s = 128; s > 0; s >>= 1) {
        if (tid < s) cnt[tid] += cnt[tid + s];
        __syncthreads();
    }
    if (tid == 0) flag[0] = (cnt[0] > 32768) ? 1 : 0;   // 1 => bf16-packed
}

__device__ __forceinline__ float load_maybe(const void* p, long i, int isbf16)
{
    return isbf16 ? __bfloat162float(((const bf16*)p)[i])
                  : ((const float*)p)[i];
}

// ---------------------------------------------------------------------------
// OLD fused GEMM (verified): kept for fallback path and layers 2/3.
// ---------------------------------------------------------------------------
__global__ __launch_bounds__(256) void gemm_kernel(
    const void* __restrict__ A1, int a1_maybe, long a1_off, int lda1, int K1,
    const float* __restrict__ A2, int lda2, int K2,
    const void* __restrict__ Wa, const void* __restrict__ Wb,
    const void* __restrict__ bias,
    const int* __restrict__ flagp,
    float* __restrict__ C, int M, int N, int do_relu)
{
    const int flagv = flagp[0];          // uniform; L2-hit
    const int a1_bf = a1_maybe ? flagv : 0;

    __shared__ float As[32][33];
    __shared__ float Bs[32][33];

    const int tid = threadIdx.x;
    const int tx = tid & 15;
    const int ty = tid >> 4;
    const int n0 = blockIdx.x * 32;
    const int m0 = blockIdx.y * 32;

    float acc00 = 0.f, acc01 = 0.f, acc10 = 0.f, acc11 = 0.f;

    for (int part = 0; part < 2; ++part) {
        const void* Wp = part ? Wb : Wa;
        const int    K = part ? K2 : K1;
        if (part == 1 && (A2 == nullptr || K2 <= 0)) continue;

        for (int k0 = 0; k0 < K; k0 += 32) {
            #pragma unroll
            for (int i = 0; i < 4; ++i) {
                int idx = tid + i * 256;
                int r = idx >> 5, c = idx & 31;
                float av;
                if (part == 0) {
                    long off = a1_off + (long)(m0 + r) * lda1 + (k0 + c);
                    av = load_maybe(A1, off, a1_bf);
                } else {
                    av = A2[(long)(m0 + r) * lda2 + (k0 + c)];
                }
                As[r][c] = av;
                int n = n0 + c;
                Bs[r][c] = (n < N) ? load_maybe(Wp, (long)(k0 + r) * N + n, flagv)
                                   : 0.0f;
            }
            __syncthreads();
            #pragma unroll
            for (int k = 0; k < 32; ++k) {
                float a0 = As[ty * 2][k];
                float a1 = As[ty * 2 + 1][k];
                float b0 = Bs[k][tx * 2];
                float b1 = Bs[k][tx * 2 + 1];
                acc00 = fmaf(a0, b0, acc00); acc01 = fmaf(a0, b1, acc01);
                acc10 = fmaf(a1, b0, acc10); acc11 = fmaf(a1, b1, acc11);
            }
            __syncthreads();
        }
    }

    const int m = m0 + ty * 2;
    const int n = n0 + tx * 2;
    float bs0 = (n     < N) ? load_maybe(bias, n,     flagv) : 0.0f;
    float bs1 = (n + 1 < N) ? load_maybe(bias, n + 1, flagv) : 0.0f;
    float v00 = acc00 + bs0, v01 = acc01 + bs1;
    float v10 = acc10 + bs0, v11 = acc11 + bs1;
    if (do_relu) {
        v00 = fmaxf(v00, 0.f); v01 = fmaxf(v01, 0.f);
        v10 = fmaxf(v10, 0.f); v11 = fmaxf(v11, 0.f);
    }
    if (n     < N) C[(long)m * N + n]           = v00;
    if (n + 1 < N) C[(long)m * N + n + 1]       = v01;
    if (n     < N) C[(long)(m + 1) * N + n]     = v10;
    if (n + 1 < N) C[(long)(m + 1) * N + n + 1] = v11;
}

// ---------------------------------------------------------------------------
// XW chunk GEMM (verified r10). C[8192][1024] = inputs_chunk @ Wx + b_rnn.
// Chunk rows r = b*32 + tl  <->  input row b*256 + (t0 + tl).
// 128x128 tile, BK=16, 8x8 micro, 256 threads. Grid (8, 64).
// ---------------------------------------------------------------------------
__global__ __launch_bounds__(256, 2) void xw_gemm_kernel(
    const void* __restrict__ X,      // inputs, dual dtype
    const void* __restrict__ Wx,     // [512][1024], dual dtype
    const void* __restrict__ brnn,   // [1024], dual dtype
    const int* __restrict__ flagp,
    float* __restrict__ C,           // [8192][1024] chunk buffer
    int t0)
{
    const int flagv = flagp[0];
    __shared__ float As[16][132];    // k-major: As[k][m]
    __shared__ float Bs[16][132];    // Bs[k][n]

    const int tid = threadIdx.x;
    const int tx = tid & 15;
    const int ty = tid >> 4;
    const int n0 = blockIdx.x * 128;
    const int m0 = blockIdx.y * 128;

    float acc[8][8] = {{0.f}};

    for (int k0 = 0; k0 < F_; k0 += 16) {
        #pragma unroll
        for (int i = 0; i < 8; ++i) {
            int idx = tid + i * 256;            // 0..2047
            // A: 128 rows x 16 k, consecutive tid -> consecutive k
            int ka = idx & 15, r = idx >> 4;
            int rg = m0 + r;
            long irow = (long)(rg >> 5) * 256 + t0 + (rg & 31);
            As[ka][r] = load_maybe(X, irow * F_ + k0 + ka, flagv);
            // B: 16 k x 128 n, consecutive tid -> consecutive n
            int nb = idx & 127, kb = idx >> 7;
            Bs[kb][nb] = load_maybe(Wx, (long)(k0 + kb) * H_ + n0 + nb, flagv);
        }
        __syncthreads();
        #pragma unroll
        for (int k = 0; k < 16; ++k) {
            float4 a0 = *(const float4*)&As[k][ty * 4];
            float4 a1 = *(const float4*)&As[k][ty * 4 + 64];
            float4 b0 = *(const float4*)&Bs[k][tx * 4];
            float4 b1 = *(const float4*)&Bs[k][tx * 4 + 64];
            float av[8] = {a0.x, a0.y, a0.z, a0.w, a1.x, a1.y, a1.z, a1.w};
            float bv[8] = {b0.x, b0.y, b0.z, b0.w, b1.x, b1.y, b1.z, b1.w};
            #pragma unroll
            for (int i = 0; i < 8; ++i)
                #pragma unroll
                for (int j = 0; j < 8; ++j)
                    acc[i][j] = fmaf(av[i], bv[j], acc[i][j]);
        }
        __syncthreads();
    }

    float bb[8];
    #pragma unroll
    for (int j = 0; j < 8; ++j) {
        int n = n0 + tx * 4 + (j & 3) + (j >> 2) * 64;
        bb[j] = load_maybe(brnn, n, flagv);
    }
    #pragma unroll
    for (int i = 0; i < 8; ++i) {
        int m = m0 + ty * 4 + (i & 3) + (i >> 2) * 64;
        float4 v0 = {acc[i][0] + bb[0], acc[i][1] + bb[1],
                     acc[i][2] + bb[2], acc[i][3] + bb[3]};
        float4 v1 = {acc[i][4] + bb[4], acc[i][5] + bb[5],
                     acc[i][6] + bb[6], acc[i][7] + bb[7]};
        *(float4*)&C[(long)m * H_ + n0 + tx * 4]      = v0;
        *(float4*)&C[(long)m * H_ + n0 + tx * 4 + 64] = v1;
    }
}

// ---------------------------------------------------------------------------
// Wh -> fp32 copy (handles bf16-packed mode once, outside the scan).
// ---------------------------------------------------------------------------
__global__ __launch_bounds__(256) void convert_wh_kernel(
    const void* __restrict__ Wh, const int* __restrict__ flagp,
    float* __restrict__ whf)
{
    const int flagv = flagp[0];
    long i = (long)blockIdx.x * 256 + threadIdx.x;
    whf[i] = load_maybe(Wh, i, flagv);
}

// ---------------------------------------------------------------------------
// r11/r12: RNN scan step v2 — in-block split-K for 4 waves/SIMD TLP.
//   hTn[n][m] = relu( xw[m][tl][n] + sum_k hT[k][m] * Wh[k][n] )
// Layouts: hT/hTn = [1024 k][256 m]; xw base already offset to tl
// (row stride 32*1024 per batch row m).
// Grid (64, 4) x 1024 threads = 16 waves/block:
//   wave w: col group g = w&3 -> cols n0 = bx*16 + g*4 .. +3 (wave-uniform)
//           k quarter q = w>>2 -> k in [q*256, q*256+256)
//   lane l: m = by*64 + l  -> hT reads coalesced 256B/wave-inst
// Combine: waves q>0 write float4 partials to LDS (12KB, contiguous b128,
// conflict-free); barrier; waves q==0 sum q0+q1+q2+q3 (fixed order), add
// xw (contains b_rnn), relu, store. 4 waves/SIMD occupancy -> TLP hides
// L2-hit latency; no manual pipeline; VGPR ~60 << 128 cap.
// ---------------------------------------------------------------------------
__global__ __launch_bounds__(1024) void rnn_step2_kernel(
    const float* __restrict__ hT,     // [1024][256]
    const float* __restrict__ Wh,     // [1024][1024] fp32
    const float* __restrict__ xw,     // xwbuf + tl*1024
    float* __restrict__ hTn)          // [1024][256]
{
    const int tid  = threadIdx.x;
    const int lane = tid & 63;
    const int w    = __builtin_amdgcn_readfirstlane(tid >> 6);
    const int g    = w & 3;            // col group
    const int q    = w >> 2;           // k quarter
    const int m    = blockIdx.y * 64 + lane;
    const int n0   = blockIdx.x * 16 + g * 4;

    // q-quarter bases: hT + q*256*256 + m ; Wh + q*256*1024 + n0
    const float* __restrict__ ap = hT + ((long)q << 16) + m;
    const float* __restrict__ bp = Wh + ((long)q << 18) + n0;

    float acc0 = 0.f, acc1 = 0.f, acc2 = 0.f, acc3 = 0.f;
    #pragma unroll 8
    for (int k = 0; k < 256; ++k) {
        float  a = ap[(long)k << 8];
        float4 b = *(const float4*)(bp + ((long)k << 10));
        acc0 = fmaf(a, b.x, acc0);
        acc1 = fmaf(a, b.y, acc1);
        acc2 = fmaf(a, b.z, acc2);
        acc3 = fmaf(a, b.w, acc3);
    }

    __shared__ float4 part[3][4][64];   // [q-1][g][lane], 12 KB
    if (q > 0) part[q - 1][g][lane] = make_float4(acc0, acc1, acc2, acc3);
    __syncthreads();

    if (q == 0) {
        float4 p0 = part[0][g][lane];
        float4 p1 = part[1][g][lane];
        float4 p2 = part[2][g][lane];
        const float4 xv = *(const float4*)(xw + (long)m * (32 * 1024) + n0);
        float s0 = ((acc0 + p0.x) + p1.x) + p2.x;
        float s1 = ((acc1 + p0.y) + p1.y) + p2.y;
        float s2 = ((acc2 + p0.z) + p1.z) + p2.z;
        float s3 = ((acc3 + p0.w) + p1.w) + p2.w;
        float v0 = fmaxf(s0 + xv.x, 0.f);
        float v1 = fmaxf(s1 + xv.y, 0.f);
        float v2 = fmaxf(s2 + xv.z, 0.f);
        float v3 = fmaxf(s3 + xv.w, 0.f);
        hTn[(long)(n0 + 0) * 256 + m] = v0;
        hTn[(long)(n0 + 1) * 256 + m] = v1;
        hTn[(long)(n0 + 2) * 256 + m] = v2;
        hTn[(long)(n0 + 3) * 256 + m] = v3;
    }
}

// ---------------------------------------------------------------------------
// transpose hT[1024][256] -> h_last[256][1024] for layer 2.
// ---------------------------------------------------------------------------
__global__ __launch_bounds__(256) void transpose_kernel(
    const float* __restrict__ in,   // [1024][256]
    float* __restrict__ out)        // [256][1024]
{
    __shared__ float t[32][33];
    const int tid = threadIdx.x;
    const int c  = tid & 31;
    const int r8 = tid >> 5;
    const int x0 = blockIdx.x * 32;   // over 1024
    const int y0 = blockIdx.y * 32;   // over 256
    #pragma unroll
    for (int i = 0; i < 4; ++i) {
        int r = r8 + i * 8;
        t[r][c] = in[(long)(x0 + r) * 256 + y0 + c];
    }
    __syncthreads();
    #pragma unroll
    for (int i = 0; i < 4; ++i) {
        int r = r8 + i * 8;
        out[(long)(y0 + r) * 1024 + x0 + c] = t[c][r];
    }
}

// ---------------------------------------------------------------------------
// Threefry2x32, 20 rounds — matches JAX exactly. key(42) => (k0,k1)=(0,42).
// ---------------------------------------------------------------------------
__device__ __forceinline__ unsigned rotl32(unsigned v, int r) {
    return (v << r) | (v >> (32 - r));
}

__device__ __forceinline__ void threefry2x32(unsigned k0, unsigned k1,
                                             unsigned x0, unsigned x1,
                                             unsigned& o0, unsigned& o1)
{
    unsigned ks2 = k0 ^ k1 ^ 0x1BD11BDAu;
    x0 += k0; x1 += k1;
#define R4(ra, rb, rc, rd)                              \
    x0 += x1; x1 = rotl32(x1, ra); x1 ^= x0;            \
    x0 += x1; x1 = rotl32(x1, rb); x1 ^= x0;            \
    x0 += x1; x1 = rotl32(x1, rc); x1 ^= x0;            \
    x0 += x1; x1 = rotl32(x1, rd); x1 ^= x0;
    R4(13, 15, 26, 6);  x0 += k1;  x1 += ks2 + 1u;
    R4(17, 29, 16, 24); x0 += ks2; x1 += k0  + 2u;
    R4(13, 15, 26, 6);  x0 += k0;  x1 += k1  + 3u;
    R4(17, 29, 16, 24); x0 += k1;  x1 += ks2 + 4u;
    R4(13, 15, 26, 6);  x0 += ks2; x1 += k0  + 5u;
#undef R4
    o0 = x0; o1 = x1;
}

// Gumbel at flat index j of the (256,1000) draw, key(42).
// V4 partitionable xor-fold (VERIFIED): counts (hi=0, lo=j), bits = o0^o1.
__device__ __forceinline__ float gumbel_at(unsigned j)
{
    unsigned o0, o1;
    threefry2x32(0u, 42u, 0u, j, o0, o1);
    unsigned bits = o0 ^ o1;                       // V4: xor-fold
    unsigned ub = (bits >> 9) | 0x3F800000u;       // [1,2)
    float u = __uint_as_float(ub) - 1.0f;          // [0,1)
    const float TINY = 1.1754943508222875e-38f;    // finfo(f32).tiny
    u = fmaxf(TINY, u * (1.0f - TINY) + TINY);     // JAX uniform(minval=tiny)
    return -logf(-logf(u));
}

// ---------------------------------------------------------------------------
// Softmax + gumbel-argmax sampling + loss. One block per batch row.
// OUTPUT IS FLOAT32. besti canary = 500.
// ---------------------------------------------------------------------------
__global__ __launch_bounds__(256) void sample_kernel(
    const float* __restrict__ logits,      // [B_, A_]
    float* __restrict__ out,               // out[b] = action as float32
    float* __restrict__ loss_acc)          // pre-zeroed scalar
{
    const int b = blockIdx.x;
    const int tid = threadIdx.x;
    const float* row = logits + (long)b * A_;

    __shared__ float sv[256];
    __shared__ int   si[256];

    // 1. row max
    float lv[4];
    float lmax = -INFINITY;
    #pragma unroll
    for (int i = 0; i < 4; ++i) {
        int a = tid + i * 256;
        lv[i] = (a < A_) ? row[a] : -INFINITY;
        lmax = fmaxf(lmax, lv[i]);
    }
    sv[tid] = lmax;
    __syncthreads();
    for (int s = 128; s > 0; s >>= 1) {
        if (tid < s) sv[tid] = fmaxf(sv[tid], sv[tid + s]);
        __syncthreads();
    }
    lmax = sv[0];
    __syncthreads();

    // 2. exp + sum
    float e[4];
    float lsum = 0.f;
    #pragma unroll
    for (int i = 0; i < 4; ++i) {
        int a = tid + i * 256;
        e[i] = (a < A_) ? expf(lv[i] - lmax) : 0.0f;
        lsum += e[i];
    }
    sv[tid] = lsum;
    __syncthreads();
    for (int s = 128; s > 0; s >>= 1) {
        if (tid < s) sv[tid] += sv[tid + s];
        __syncthreads();
    }
    const float inv = 1.0f / sv[0];
    __syncthreads();

    // 3. score = prob + gumbel; argmax, first-index tie-break (np.argmax)
    float bestv = -INFINITY;
    int   besti = 500;                     // NaN canary
    #pragma unroll
    for (int i = 0; i < 4; ++i) {
        int a = tid + i * 256;
        if (a < A_) {
            float score = e[i] * inv + gumbel_at((unsigned)(b * A_ + a));
            if (score > bestv) { bestv = score; besti = a; }
        }
    }
    sv[tid] = bestv; si[tid] = besti;
    __syncthreads();
    for (int s = 128; s > 0; s >>= 1) {
        if (tid < s) {
            float v2 = sv[tid + s]; int i2 = si[tid + s];
            if (v2 > sv[tid] || (v2 == sv[tid] && i2 < si[tid])) {
                sv[tid] = v2; si[tid] = i2;
            }
        }
        __syncthreads();
    }

    if (tid == 0) {
        int act = si[0];
        out[b] = (float)act;                       // float32 action
        float p = expf(row[act] - lmax) * inv;
        p = fminf(fmaxf(p, EPS_), 1.0f - EPS_);
        atomicAdd(loss_acc, -logf(p) * (1.0f / (float)B_));
    }
}

__global__ void finalize_kernel(const float* __restrict__ loss_acc,
                                float* __restrict__ out)
{
    out[B_] = *loss_acc;                           // float32 loss
}

// ---------------------------------------------------------------------------
extern "C" void kernel_launch(void* const* d_in, const int* in_sizes, int n_in,
                              void* d_out, int out_size, void* d_ws, size_t ws_size,
                              hipStream_t stream)
{
    (void)out_size;

    // Size-based pointer mapping (removes any ordering assumption).
    const void *inputs = nullptr, *Wx = nullptr, *Wh = nullptr, *b_rnn = nullptr,
               *W1 = nullptr, *b1 = nullptr, *W2 = nullptr, *b2 = nullptr;
    for (int i = 0; i < n_in; ++i) {
        int s = in_sizes[i];
        if      (s == 33554432) inputs = d_in[i];
        else if (s == 524288)   Wx = d_in[i];
        else if (s == 1048576)  { if (!Wh) Wh = d_in[i]; else W1 = d_in[i]; }
        else if (s == 1024)     { if (!b_rnn) b_rnn = d_in[i]; else b1 = d_in[i]; }
        else if (s == 1024000)  W2 = d_in[i];
        else if (s == 1000)     b2 = d_in[i];
    }
    if (!inputs) inputs = d_in[0];
    if (!Wx) Wx = d_in[1];  if (!Wh) Wh = d_in[2];  if (!b_rnn) b_rnn = d_in[3];
    if (!W1) W1 = d_in[4];  if (!b1) b1 = d_in[5];  if (!W2) W2 = d_in[6];
    if (!b2) b2 = d_in[7];

    float* out = (float*)d_out;            // FLOAT32 output buffer
    float* ws = (float*)d_ws;

    dim3 blk(256);
    dim3 grdH((H_ + 31) / 32, B_ / 32);   // 32 x 8
    dim3 grdA((A_ + 31) / 32, B_ / 32);

    // Workspace demand for the fast path (~43 MB in floats):
    const size_t XW_FLOATS = (size_t)8192 * 1024;     // 8,388,608 (32-t chunk)
    const size_t need_floats = XW_FLOATS + 2 * 262144 + 1048576
                             + 262144 + 262144 + 256000 + 2;
    if (ws_size >= need_floats * sizeof(float)) {
        // ---------------- FAST PATH (round 12) ----------------
        float* xwbuf    = ws;                          // [8192][1024]
        float* hT0      = xwbuf + XW_FLOATS;           // [1024][256]
        float* hT1      = hT0 + 262144;                // [1024][256]
        float* whf      = hT1 + 262144;                // [1024][1024]
        float* hlast    = whf + 1048576;               // [256][1024]
        float* hid      = hlast + 262144;              // [256][1024]
        float* logits   = hid + 262144;                // [256][1000]
        float* loss_acc = logits + 256000;             // [1]
        int*   flag     = (int*)(loss_acc + 1);        // [1]

        hipMemsetAsync(hT0, 0, 262144 * sizeof(float), stream);
        hipMemsetAsync(loss_acc, 0, sizeof(float), stream);

        // 0. dtype detect, Wh -> fp32
        detect_kernel<<<1, blk, 0, stream>>>((const unsigned*)Wx, flag);
        convert_wh_kernel<<<4096, blk, 0, stream>>>(Wh, flag, whf);

        // 1. scan: per 32-t chunk, precompute XW then run 32 steps
        float* hp = hT0;
        float* hn = hT1;
        for (int c = 0; c < 8; ++c) {
            xw_gemm_kernel<<<dim3(8, 64), blk, 0, stream>>>(
                inputs, Wx, b_rnn, flag, xwbuf, c * 32);
            for (int tl = 0; tl < 32; ++tl) {
                rnn_step2_kernel<<<dim3(64, 4), dim3(1024), 0, stream>>>(
                    hp, whf, xwbuf + (long)tl * 1024, hn);
                float* tmp = hp; hp = hn; hn = tmp;
            }
        }

        // 2. hT -> h_last (natural layout) for the dense layers
        transpose_kernel<<<dim3(32, 8), blk, 0, stream>>>(hp, hlast);

        // 3. hid = relu(h_T @ W1 + b1); logits = hid @ W2 + b2
        gemm_kernel<<<grdH, blk, 0, stream>>>(
            hlast, 0, 0, H_, H_, nullptr, 0, 0, W1, nullptr, b1, flag,
            hid, B_, H_, 1);
        gemm_kernel<<<grdA, blk, 0, stream>>>(
            hid, 0, 0, H_, H_, nullptr, 0, 0, W2, nullptr, b2, flag,
            logits, B_, A_, 0);

        // 4. softmax -> gumbel argmax -> loss
        sample_kernel<<<dim3(B_), blk, 0, stream>>>(logits, out, loss_acc);
        finalize_kernel<<<1, 1, 0, stream>>>(loss_acc, out);
        return;
    }

    // ---------------- FALLBACK: verbatim verified path ----------------
    float* hA       = ws;                       // [B,H]
    float* hB       = hA + (long)B_ * H_;       // [B,H]
    float* hid      = hB + (long)B_ * H_;       // [B,H]
    float* logits   = hid + (long)B_ * H_;      // [B,A]
    float* loss_acc = logits + (long)B_ * A_;   // [1]
    int*   flag     = (int*)(loss_acc + 1);     // [1] dtype flag

    hipMemsetAsync(hA, 0, (size_t)B_ * H_ * sizeof(float), stream);
    hipMemsetAsync(loss_acc, 0, sizeof(float), stream);

    detect_kernel<<<1, blk, 0, stream>>>((const unsigned*)Wx, flag);

    float* hp = hA;
    float* hn = hB;
    for (int t = 0; t < T_; ++t) {
        gemm_kernel<<<grdH, blk, 0, stream>>>(
            inputs, 1, (long)t * F_, T_ * F_, F_,
            hp, H_, H_,
            Wx, Wh, b_rnn, flag,
            hn, B_, H_, 1);
        float* tmp = hp; hp = hn; hn = tmp;
    }

    gemm_kernel<<<grdH, blk, 0, stream>>>(
        hp, 0, 0, H_, H_, nullptr, 0, 0, W1, nullptr, b1, flag, hid, B_, H_, 1);
    gemm_kernel<<<grdA, blk, 0, stream>>>(
        hid, 0, 0, H_, H_, nullptr, 0, 0, W2, nullptr, b2, flag, logits, B_, A_, 0);

    sample_kernel<<<dim3(B_), blk, 0, stream>>>(logits, out, loss_acc);
    finalize_kernel<<<1, 1, 0, stream>>>(loss_acc, out);
}